// Round 5
// baseline (874.361 us; speedup 1.0000x reference)
//
#include <hip/hip_runtime.h>
#include <hip/hip_bf16.h>

#define HC   256   // H * C (heads * per-head channels)
#define FIN  32    // input feature dim of each GAT layer
#define NH   8     // heads
#define CAP  128   // edge chunk per LDS pass in fused agg

typedef __hip_bfloat16 bf16;

__device__ __forceinline__ float blo(unsigned int u) { return __uint_as_float(u << 16); }
__device__ __forceinline__ float bhi(unsigned int u) { return __uint_as_float(u & 0xffff0000u); }

// ---------------- CSR build (dst is identical for both layers) ----------------
__global__ void count_kernel(const int* __restrict__ dst, int* __restrict__ cnt, int E_) {
  int e = blockIdx.x * blockDim.x + threadIdx.x;
  if (e < E_) atomicAdd(&cnt[dst[e]], 1);
}

__global__ void scan_kernel(const int* __restrict__ cnt, int* __restrict__ rowptr,
                            int* __restrict__ fill, int N_, int E_) {
  __shared__ int part[1024];
  int t = threadIdx.x;
  int chunk = (N_ + 1023) / 1024;
  int lo = t * chunk, hi = lo + chunk;
  if (lo > N_) lo = N_;
  if (hi > N_) hi = N_;
  int s = 0;
  for (int i = lo; i < hi; ++i) s += cnt[i];
  part[t] = s;
  __syncthreads();
  // Hillis-Steele inclusive scan over 1024 partials
  for (int off = 1; off < 1024; off <<= 1) {
    int v = (t >= off) ? part[t - off] : 0;
    __syncthreads();
    part[t] += v;
    __syncthreads();
  }
  int run = part[t] - s;   // exclusive prefix for this thread's chunk
  for (int i = lo; i < hi; ++i) { rowptr[i] = run; fill[i] = run; run += cnt[i]; }
  if (t == 0) rowptr[N_] = E_;
}

// scatter edges into CSR order; emit per-position src array
__global__ void scatter_kernel(const int* __restrict__ src, const int* __restrict__ dst,
                               int* __restrict__ fill, int* __restrict__ perm,
                               int* __restrict__ srcs, int E_) {
  int e = blockIdx.x * blockDim.x + threadIdx.x;
  if (e < E_) {
    int pos = atomicAdd(&fill[dst[e]], 1);
    perm[pos] = e;
    srcs[pos] = src[e];
  }
}

// ---------------- fold We[8,256] x a_e[8,32] -> M[8,8] for both layers --------
__global__ void fold_kernel(const float* __restrict__ We1, const float* __restrict__ ae1,
                            const float* __restrict__ We2, const float* __restrict__ ae2,
                            float* __restrict__ M) {
  int t = threadIdx.x;             // 0..127
  const float* We = (t < 64) ? We1 : We2;
  const float* ae = (t < 64) ? ae1 : ae2;
  int i = t & 63;
  int k = i >> 3, hh = i & 7;
  float s = 0.f;
  for (int c = 0; c < FIN; ++c)
    s = fmaf(We[k * HC + hh * FIN + c], ae[hh * FIN + c], s);
  M[t] = s;                        // M[layer*64 + k*8 + hh]
}

// -------- h = x@W (bf16 store) + per-head logits; 4 nodes per block ----------
__global__ __launch_bounds__(256) void
node_kernel(const float* __restrict__ emb, const int* __restrict__ node_ids,
            const float* __restrict__ xin,
            const float* __restrict__ W,
            const float* __restrict__ a_src, const float* __restrict__ a_dst,
            bf16* __restrict__ h, float* __restrict__ alsrc,
            float* __restrict__ aldst, int N_) {
  int n0 = blockIdx.x * 4, t = threadIdx.x;
  __shared__ float xs[4][FIN];
  if (t < 128) {
    int nb = t >> 5, k = t & 31;
    int n = n0 + nb;
    if (n < N_) {
      if (node_ids) xs[nb][k] = emb[(size_t)node_ids[n] * FIN + k];
      else          xs[nb][k] = xin[(size_t)n * FIN + k];
    }
  }
  __syncthreads();
  float was = a_src[t], wad = a_dst[t];
  float acc0 = 0.f, acc1 = 0.f, acc2 = 0.f, acc3 = 0.f;
#pragma unroll
  for (int k = 0; k < FIN; ++k) {
    float w = W[k * HC + t];
    acc0 = fmaf(xs[0][k], w, acc0);
    acc1 = fmaf(xs[1][k], w, acc1);
    acc2 = fmaf(xs[2][k], w, acc2);
    acc3 = fmaf(xs[3][k], w, acc3);
  }
  float accs[4] = {acc0, acc1, acc2, acc3};
#pragma unroll
  for (int nb = 0; nb < 4; ++nb) {
    int n = n0 + nb;
    if (n >= N_) break;
    float a = accs[nb];
    h[(size_t)n * HC + t] = __float2bfloat16(a);
    float v = a * was;
#pragma unroll
    for (int off = 16; off >= 1; off >>= 1) v += __shfl_xor(v, off, 32);
    if ((t & 31) == 0) alsrc[(size_t)n * NH + (t >> 5)] = v;
    float u = a * wad;
#pragma unroll
    for (int off = 16; off >= 1; off >>= 1) u += __shfl_xor(u, off, 32);
    if ((t & 31) == 0) aldst[(size_t)n * NH + (t >> 5)] = u;
  }
}

// ---- fused per-dst-node: edge logits + softmax + gather + bias/relu + lin ---
template <int K, int LOG2K>
__global__ __launch_bounds__(256) void
agg_fused_kernel(const int* __restrict__ rowptr, const int* __restrict__ perm,
                 const int* __restrict__ srcs,
                 const float* __restrict__ edge_attr, const float* __restrict__ M,
                 const float* __restrict__ alsrc, const float* __restrict__ aldst,
                 const uint2* __restrict__ hp,     // h rows as 64 x uint2 (4 bf16 each)
                 const float* __restrict__ b,
                 const float* __restrict__ Wlin, const float* __restrict__ blin,
                 float* __restrict__ xout) {
  int n = blockIdx.x, t = threadIdx.x;
  __shared__ float exl[CAP * NH];   // 4 KB: exp(alpha) for current chunk
  __shared__ float Ms[64];
  __shared__ float ald[NH];
  __shared__ float den[NH];
  __shared__ float4 red4[256];      // 4 KB combine buffer
  __shared__ float gs[HC];
  __shared__ float red3[256];

  int beg = rowptr[n], end = rowptr[n + 1];
  if (t < 64) Ms[t] = M[t];
  if (t < NH) { ald[t] = aldst[(size_t)n * NH + t]; den[t] = 0.f; }
  __syncthreads();

  int q = t & 63, slot = t >> 6;    // channels 4q..4q+3, 4 edge slots
  int head = q >> 3;
  float a0 = 0.f, a1 = 0.f, a2 = 0.f, a3 = 0.f;

  for (int cbeg = beg; cbeg < end; cbeg += CAP) {
    int clen = end - cbeg; if (clen > CAP) clen = CAP;
    // phase A: compute ex for this chunk into LDS
    if (t < clen) {
      int j = cbeg + t;
      int e = perm[j];
      int sn = srcs[j];
      const float4* eap = (const float4*)(edge_attr + (size_t)e * NH);
      float4 ea0 = eap[0], ea1 = eap[1];
      float ea[NH] = {ea0.x, ea0.y, ea0.z, ea0.w, ea1.x, ea1.y, ea1.z, ea1.w};
      const float4* asp = (const float4*)(alsrc + (size_t)sn * NH);
      float4 as0 = asp[0], as1 = asp[1];
      float als[NH] = {as0.x, as0.y, as0.z, as0.w, as1.x, as1.y, as1.z, as1.w};
#pragma unroll
      for (int hh = 0; hh < NH; ++hh) {
        float al = 0.f;
#pragma unroll
        for (int k = 0; k < NH; ++k) al = fmaf(ea[k], Ms[k * NH + hh], al);
        float aa = als[hh] + ald[hh] + al;
        aa = (aa >= 0.f) ? aa : 0.2f * aa;   // leaky_relu 0.2
        exl[t * NH + hh] = __expf(aa) ;      // fast exp; alphas are O(0.1)
      }
    }
    __syncthreads();
    // denominators (t<8): serial over chunk, stride-8 LDS
    if (t < NH) {
      float s = 0.f;
      for (int j3 = 0; j3 < clen; ++j3) s += exl[j3 * NH + t];
      den[t] += s;
    }
    // phase B: weighted gather, 4 edges concurrent (slots) x 2 unroll
    int j2 = 0;
    for (; j2 + 7 < clen; j2 += 8) {
      int ja = j2 + slot, jb = ja + 4;
      int sA = srcs[cbeg + ja], sB = srcs[cbeg + jb];
      float wA = exl[ja * NH + head], wB = exl[jb * NH + head];
      uint2 hA = hp[(size_t)sA * 64 + q];
      uint2 hB = hp[(size_t)sB * 64 + q];
      a0 = fmaf(blo(hA.x), wA, a0); a1 = fmaf(bhi(hA.x), wA, a1);
      a2 = fmaf(blo(hA.y), wA, a2); a3 = fmaf(bhi(hA.y), wA, a3);
      a0 = fmaf(blo(hB.x), wB, a0); a1 = fmaf(bhi(hB.x), wB, a1);
      a2 = fmaf(blo(hB.y), wB, a2); a3 = fmaf(bhi(hB.y), wB, a3);
    }
    for (; j2 < clen; j2 += 4) {
      int ja = j2 + slot;
      if (ja < clen) {
        int sA = srcs[cbeg + ja];
        float wA = exl[ja * NH + head];
        uint2 hA = hp[(size_t)sA * 64 + q];
        a0 = fmaf(blo(hA.x), wA, a0); a1 = fmaf(bhi(hA.x), wA, a1);
        a2 = fmaf(blo(hA.y), wA, a2); a3 = fmaf(bhi(hA.y), wA, a3);
      }
    }
    __syncthreads();   // exl/den stable before next chunk overwrite
  }

  // combine 4 slots, normalize, bias, relu -> gs
  red4[t] = make_float4(a0, a1, a2, a3);
  __syncthreads();
  if (t < 64) {
    float4 r0 = red4[t], r1 = red4[t + 64], r2 = red4[t + 128], r3 = red4[t + 192];
    float rden = 1.0f / (den[t >> 3] + 1e-16f);
    float v0 = (r0.x + r1.x + r2.x + r3.x) * rden + b[4 * t + 0];
    float v1 = (r0.y + r1.y + r2.y + r3.y) * rden + b[4 * t + 1];
    float v2 = (r0.z + r1.z + r2.z + r3.z) * rden + b[4 * t + 2];
    float v3 = (r0.w + r1.w + r2.w + r3.w) * rden + b[4 * t + 3];
    gs[4 * t + 0] = (v0 > 0.f) ? v0 : 0.f;
    gs[4 * t + 1] = (v1 > 0.f) ? v1 : 0.f;
    gs[4 * t + 2] = (v2 > 0.f) ? v2 : 0.f;
    gs[4 * t + 3] = (v3 > 0.f) ? v3 : 0.f;
  }
  __syncthreads();

  // fused dense: xout[n,k] = sum_j gs[j] * Wlin[j*K+k] + blin[k]
  {
    int k = t & (K - 1), r = t >> LOG2K;
    float part = 0.f;
#pragma unroll
    for (int i = 0; i < K; ++i) {
      int jj = r * K + i;
      part = fmaf(gs[jj], Wlin[jj * K + k], part);
    }
    red3[t] = part;
    __syncthreads();
    if (t < K) {
      float s = blin[t];
#pragma unroll
      for (int r2 = 0; r2 < 256 / K; ++r2) s += red3[r2 * K + t];
      xout[(size_t)n * K + t] = s;
    }
  }
}

// ---------------- classifier: sigmoid(sum(fu*fm)) ----------------------------
__global__ void clf_kernel(const int* __restrict__ eli, const float* __restrict__ ela,
                           const float* __restrict__ x2, const float* __restrict__ clfW,
                           const float* __restrict__ clfb, float* __restrict__ out, int L_) {
  int i = blockIdx.x * blockDim.x + threadIdx.x;
  if (i >= L_) return;
  int u = eli[i], m = eli[L_ + i];
  const float4* xup = (const float4*)(x2 + (size_t)u * NH);
  const float4* xmp = (const float4*)(x2 + (size_t)m * NH);
  const float4* eap = (const float4*)(ela + (size_t)i * NH);
  float4 xu0 = xup[0], xu1 = xup[1];
  float4 xm0 = xmp[0], xm1 = xmp[1];
  float4 el0 = eap[0], el1 = eap[1];
  float xu[NH] = {xu0.x, xu0.y, xu0.z, xu0.w, xu1.x, xu1.y, xu1.z, xu1.w};
  float xm[NH] = {xm0.x, xm0.y, xm0.z, xm0.w, xm1.x, xm1.y, xm1.z, xm1.w};
  float el[NH] = {el0.x, el0.y, el0.z, el0.w, el1.x, el1.y, el1.z, el1.w};
  float fu[NH];
#pragma unroll
  for (int k = 0; k < NH; ++k) fu[k] = clfb[k];
#pragma unroll
  for (int j = 0; j < NH; ++j) {
#pragma unroll
    for (int k = 0; k < NH; ++k) fu[k] = fmaf(xu[j], clfW[j * NH + k], fu[k]);
  }
#pragma unroll
  for (int j = 0; j < NH; ++j) {
#pragma unroll
    for (int k = 0; k < NH; ++k) fu[k] = fmaf(el[j], clfW[(NH + j) * NH + k], fu[k]);
  }
  float dot = 0.f;
#pragma unroll
  for (int k = 0; k < NH; ++k) dot += fu[k] * xm[k];
  out[i] = 1.f / (1.f + expf(-dot));
}

extern "C" void kernel_launch(void* const* d_in, const int* in_sizes, int n_in,
                              void* d_out, int out_size, void* d_ws, size_t ws_size,
                              hipStream_t stream) {
  const int* node_ids   = (const int*)d_in[0];
  const int* edge_index = (const int*)d_in[1];
  const int* eli        = (const int*)d_in[2];
  // d_in[3] = topic (unused)
  const float* edge_attr = (const float*)d_in[4];
  const float* ela       = (const float*)d_in[5];
  const float* emb       = (const float*)d_in[6];
  const float* W1     = (const float*)d_in[7];
  const float* a_src1 = (const float*)d_in[8];
  const float* a_dst1 = (const float*)d_in[9];
  const float* We1    = (const float*)d_in[10];
  const float* a_e1   = (const float*)d_in[11];
  const float* b1     = (const float*)d_in[12];
  const float* lin1W  = (const float*)d_in[13];
  const float* lin1b  = (const float*)d_in[14];
  const float* W2     = (const float*)d_in[15];
  const float* a_src2 = (const float*)d_in[16];
  const float* a_dst2 = (const float*)d_in[17];
  const float* We2    = (const float*)d_in[18];
  const float* a_e2   = (const float*)d_in[19];
  const float* b2     = (const float*)d_in[20];
  const float* lin5W  = (const float*)d_in[21];
  const float* lin5b  = (const float*)d_in[22];
  const float* clfW   = (const float*)d_in[23];
  const float* clfb   = (const float*)d_in[24];

  const int N_ = in_sizes[0];
  const int E_ = in_sizes[1] / 2;
  const int L_ = in_sizes[2] / 2;
  const int* src  = edge_index;
  const int* dstp = edge_index + E_;

  char* p = (char*)d_ws;
  auto carve = [&](size_t bytes) -> char* {
    char* r = p;
    p += (bytes + 255) & ~(size_t)255;
    return r;
  };
  bf16*  hbuf   = (bf16*)carve((size_t)N_ * HC * 2);    // 25.6 MB (bf16)
  float* alsrc  = (float*)carve((size_t)N_ * NH * 4);
  float* aldst  = (float*)carve((size_t)N_ * NH * 4);
  float* x1b    = (float*)carve((size_t)N_ * FIN * 4);
  float* x2b    = (float*)carve((size_t)N_ * NH * 4);
  float* Mbuf   = (float*)carve(128 * 4);
  int*   cnt    = (int*)carve((size_t)N_ * 4);
  int*   rowptr = (int*)carve((size_t)(N_ + 1) * 4);
  int*   fill   = (int*)carve((size_t)N_ * 4);
  int*   perm   = (int*)carve((size_t)E_ * 4);
  int*   srcs   = (int*)carve((size_t)E_ * 4);

  hipMemsetAsync(cnt, 0, (size_t)N_ * 4, stream);
  int eb = (E_ + 255) / 256;
  count_kernel<<<eb, 256, 0, stream>>>(dstp, cnt, E_);
  scan_kernel<<<1, 1024, 0, stream>>>(cnt, rowptr, fill, N_, E_);
  scatter_kernel<<<eb, 256, 0, stream>>>(src, dstp, fill, perm, srcs, E_);
  fold_kernel<<<1, 128, 0, stream>>>(We1, a_e1, We2, a_e2, Mbuf);

  int nb4 = (N_ + 3) / 4;
  // ---- layer 1 ----
  node_kernel<<<nb4, 256, 0, stream>>>(emb, node_ids, nullptr, W1, a_src1, a_dst1,
                                       hbuf, alsrc, aldst, N_);
  agg_fused_kernel<32, 5><<<N_, 256, 0, stream>>>(rowptr, perm, srcs, edge_attr, Mbuf,
                                                  alsrc, aldst, (const uint2*)hbuf,
                                                  b1, lin1W, lin1b, x1b);

  // ---- layer 2 ----
  node_kernel<<<nb4, 256, 0, stream>>>(nullptr, nullptr, x1b, W2, a_src2, a_dst2,
                                       hbuf, alsrc, aldst, N_);
  agg_fused_kernel<8, 3><<<N_, 256, 0, stream>>>(rowptr, perm, srcs, edge_attr, Mbuf + 64,
                                                 alsrc, aldst, (const uint2*)hbuf,
                                                 b2, lin5W, lin5b, x2b);

  // ---- classifier ----
  clf_kernel<<<(L_ + 255) / 256, 256, 0, stream>>>(eli, ela, x2b, clfW, clfb,
                                                   (float*)d_out, L_);
}

// Round 6
// 725.950 us; speedup vs baseline: 1.2044x; 1.2044x over previous
//
#include <hip/hip_runtime.h>
#include <hip/hip_bf16.h>

#define HC   256   // H * C (heads * per-head channels)
#define FIN  32    // input feature dim of each GAT layer
#define NH   8     // heads

typedef __hip_bfloat16 bf16;

__device__ __forceinline__ float blo(unsigned int u) { return __uint_as_float(u << 16); }
__device__ __forceinline__ float bhi(unsigned int u) { return __uint_as_float(u & 0xffff0000u); }

// ---------------- CSR build (dst is identical for both layers) ----------------
__global__ void count_kernel(const int* __restrict__ dst, int* __restrict__ cnt, int E_) {
  int e = blockIdx.x * blockDim.x + threadIdx.x;
  if (e < E_) atomicAdd(&cnt[dst[e]], 1);
}

__global__ void scan_kernel(const int* __restrict__ cnt, int* __restrict__ rowptr,
                            int* __restrict__ fill, int N_, int E_) {
  __shared__ int part[1024];
  int t = threadIdx.x;
  int chunk = (N_ + 1023) / 1024;
  int lo = t * chunk, hi = lo + chunk;
  if (lo > N_) lo = N_;
  if (hi > N_) hi = N_;
  int s = 0;
  for (int i = lo; i < hi; ++i) s += cnt[i];
  part[t] = s;
  __syncthreads();
  // Hillis-Steele inclusive scan over 1024 partials
  for (int off = 1; off < 1024; off <<= 1) {
    int v = (t >= off) ? part[t - off] : 0;
    __syncthreads();
    part[t] += v;
    __syncthreads();
  }
  int run = part[t] - s;   // exclusive prefix for this thread's chunk
  for (int i = lo; i < hi; ++i) { rowptr[i] = run; fill[i] = run; run += cnt[i]; }
  if (t == 0) rowptr[N_] = E_;
}

// scatter edges into CSR order; emit per-position src and dst arrays
__global__ void scatter_kernel(const int* __restrict__ src, const int* __restrict__ dst,
                               int* __restrict__ fill, int* __restrict__ perm,
                               int* __restrict__ srcs, int* __restrict__ dsts, int E_) {
  int e = blockIdx.x * blockDim.x + threadIdx.x;
  if (e < E_) {
    int d = dst[e];
    int pos = atomicAdd(&fill[d], 1);
    perm[pos] = e;
    srcs[pos] = src[e];
    dsts[pos] = d;
  }
}

// ---------------- fold We[8,256] x a_e[8,32] -> M[8,8] for both layers --------
__global__ void fold_kernel(const float* __restrict__ We1, const float* __restrict__ ae1,
                            const float* __restrict__ We2, const float* __restrict__ ae2,
                            float* __restrict__ M) {
  int t = threadIdx.x;             // 0..127
  const float* We = (t < 64) ? We1 : We2;
  const float* ae = (t < 64) ? ae1 : ae2;
  int i = t & 63;
  int k = i >> 3, hh = i & 7;
  float s = 0.f;
  for (int c = 0; c < FIN; ++c)
    s = fmaf(We[k * HC + hh * FIN + c], ae[hh * FIN + c], s);
  M[t] = s;                        // M[layer*64 + k*8 + hh]
}

// -------- h = x@W (bf16 store) + per-head logits; 4 nodes per block ----------
__global__ __launch_bounds__(256) void
node_kernel(const float* __restrict__ emb, const int* __restrict__ node_ids,
            const float* __restrict__ xin,
            const float* __restrict__ W,
            const float* __restrict__ a_src, const float* __restrict__ a_dst,
            bf16* __restrict__ h, float* __restrict__ alsrc,
            float* __restrict__ aldst, int N_) {
  int n0 = blockIdx.x * 4, t = threadIdx.x;
  __shared__ float xs[4][FIN];
  if (t < 128) {
    int nb = t >> 5, k = t & 31;
    int n = n0 + nb;
    if (n < N_) {
      if (node_ids) xs[nb][k] = emb[(size_t)node_ids[n] * FIN + k];
      else          xs[nb][k] = xin[(size_t)n * FIN + k];
    }
  }
  __syncthreads();
  float was = a_src[t], wad = a_dst[t];
  float acc0 = 0.f, acc1 = 0.f, acc2 = 0.f, acc3 = 0.f;
#pragma unroll
  for (int k = 0; k < FIN; ++k) {
    float w = W[k * HC + t];
    acc0 = fmaf(xs[0][k], w, acc0);
    acc1 = fmaf(xs[1][k], w, acc1);
    acc2 = fmaf(xs[2][k], w, acc2);
    acc3 = fmaf(xs[3][k], w, acc3);
  }
  float accs[4] = {acc0, acc1, acc2, acc3};
#pragma unroll
  for (int nb = 0; nb < 4; ++nb) {
    int n = n0 + nb;
    if (n >= N_) break;
    float a = accs[nb];
    h[(size_t)n * HC + t] = __float2bfloat16(a);
    float v = a * was;
#pragma unroll
    for (int off = 16; off >= 1; off >>= 1) v += __shfl_xor(v, off, 32);
    if ((t & 31) == 0) alsrc[(size_t)n * NH + (t >> 5)] = v;
    float u = a * wad;
#pragma unroll
    for (int off = 16; off >= 1; off >>= 1) u += __shfl_xor(u, off, 32);
    if ((t & 31) == 0) aldst[(size_t)n * NH + (t >> 5)] = u;
  }
}

// ---------------- per-CSR-position: ex = exp(leaky_relu(alpha)), coalesced out
__global__ void edge_kernel(const int* __restrict__ perm, const int* __restrict__ srcs,
                            const int* __restrict__ dsts,
                            const float* __restrict__ edge_attr, const float* __restrict__ M,
                            const float* __restrict__ alsrc, const float* __restrict__ aldst,
                            float* __restrict__ ex_s, int E_) {
  int j = blockIdx.x * blockDim.x + threadIdx.x;
  if (j >= E_) return;
  int e = perm[j];
  int s = srcs[j], d = dsts[j];
  const float4* eap = (const float4*)(edge_attr + (size_t)e * NH);
  float4 ea0 = eap[0], ea1 = eap[1];
  float ea[NH] = {ea0.x, ea0.y, ea0.z, ea0.w, ea1.x, ea1.y, ea1.z, ea1.w};
  const float4* asp = (const float4*)(alsrc + (size_t)s * NH);
  const float4* adp = (const float4*)(aldst + (size_t)d * NH);
  float4 as0 = asp[0], as1 = asp[1];
  float4 ad0 = adp[0], ad1 = adp[1];
  float als[NH] = {as0.x, as0.y, as0.z, as0.w, as1.x, as1.y, as1.z, as1.w};
  float ald[NH] = {ad0.x, ad0.y, ad0.z, ad0.w, ad1.x, ad1.y, ad1.z, ad1.w};
  float out[NH];
#pragma unroll
  for (int hh = 0; hh < NH; ++hh) {
    float al = 0.f;
#pragma unroll
    for (int k = 0; k < NH; ++k) al = fmaf(ea[k], M[k * NH + hh], al);
    float a = als[hh] + ald[hh] + al;
    a = (a >= 0.f) ? a : 0.2f * a;     // leaky_relu, slope 0.2
    out[hh] = __expf(a);               // max-shift skipped: alphas are O(0.1)
  }
  float4* exp4 = (float4*)(ex_s + (size_t)j * NH);
  exp4[0] = make_float4(out[0], out[1], out[2], out[3]);
  exp4[1] = make_float4(out[4], out[5], out[6], out[7]);
}

// ------- per-dst-node: softmax-weighted gather + bias + relu + fused lin -----
// gather: slot = wave (t>>6) handles one edge; 64 lanes x uint2 = full 512B row
template <int K, int LOG2K>
__global__ __launch_bounds__(256) void
agg_lin_kernel(const int* __restrict__ rowptr, const int* __restrict__ srcs,
               const float* __restrict__ ex_s, const uint2* __restrict__ hp,
               const float* __restrict__ b,
               const float* __restrict__ Wlin, const float* __restrict__ blin,
               float* __restrict__ xout) {
  int n = blockIdx.x, t = threadIdx.x;
  __shared__ float4 red4[256];      // 4 KB; first 1 KB aliased as float red[256]
  __shared__ float gs[HC];
  __shared__ float sden[NH];
  float* red = (float*)red4;

  int beg = rowptr[n], end = rowptr[n + 1];

  // phase 1: denominators — coalesced strided read over ex_s[beg*8 .. end*8)
  {
    float part = 0.f;
    for (int q = beg * NH + t; q < end * NH; q += 256) part += ex_s[q];
    red[t] = part;                 // head of this partial = t & 7 (256 % 8 == 0)
    __syncthreads();
    if (t < NH) {
      float s = 0.f;
#pragma unroll
      for (int i = 0; i < 32; ++i) s += red[t + NH * i];
      sden[t] = 1.0f / (s + 1e-16f);
    }
    __syncthreads();
  }

  // phase 2: weighted gather; each wave (slot) owns one edge per step
  int q = t & 63, slot = t >> 6;    // lane q covers channels 4q..4q+3
  int head = q >> 3;
  float a0 = 0.f, a1 = 0.f, a2 = 0.f, a3 = 0.f;
  int j = beg;
  for (; j + 7 < end; j += 8) {
    int ja = j + slot, jb = ja + 4;
    int sA = srcs[ja], sB = srcs[jb];
    float wA = ex_s[(size_t)ja * NH + head];
    float wB = ex_s[(size_t)jb * NH + head];
    uint2 hA = hp[(size_t)sA * 64 + q];
    uint2 hB = hp[(size_t)sB * 64 + q];
    a0 = fmaf(blo(hA.x), wA, a0); a1 = fmaf(bhi(hA.x), wA, a1);
    a2 = fmaf(blo(hA.y), wA, a2); a3 = fmaf(bhi(hA.y), wA, a3);
    a0 = fmaf(blo(hB.x), wB, a0); a1 = fmaf(bhi(hB.x), wB, a1);
    a2 = fmaf(blo(hB.y), wB, a2); a3 = fmaf(bhi(hB.y), wB, a3);
  }
  for (; j < end; j += 4) {
    int ja = j + slot;
    if (ja < end) {
      int sA = srcs[ja];
      float wA = ex_s[(size_t)ja * NH + head];
      uint2 hA = hp[(size_t)sA * 64 + q];
      a0 = fmaf(blo(hA.x), wA, a0); a1 = fmaf(bhi(hA.x), wA, a1);
      a2 = fmaf(blo(hA.y), wA, a2); a3 = fmaf(bhi(hA.y), wA, a3);
    }
  }
  __syncthreads();                  // phase-1 reads of red[] complete
  red4[t] = make_float4(a0, a1, a2, a3);
  __syncthreads();
  if (t < 64) {
    float4 r0 = red4[t], r1 = red4[t + 64], r2 = red4[t + 128], r3 = red4[t + 192];
    float rden = sden[t >> 3];      // channels 4t..4t+3 all in head t>>3
    float v0 = (r0.x + r1.x + r2.x + r3.x) * rden + b[4 * t + 0];
    float v1 = (r0.y + r1.y + r2.y + r3.y) * rden + b[4 * t + 1];
    float v2 = (r0.z + r1.z + r2.z + r3.z) * rden + b[4 * t + 2];
    float v3 = (r0.w + r1.w + r2.w + r3.w) * rden + b[4 * t + 3];
    gs[4 * t + 0] = (v0 > 0.f) ? v0 : 0.f;
    gs[4 * t + 1] = (v1 > 0.f) ? v1 : 0.f;
    gs[4 * t + 2] = (v2 > 0.f) ? v2 : 0.f;
    gs[4 * t + 3] = (v3 > 0.f) ? v3 : 0.f;
  }
  __syncthreads();

  // phase 3: fused dense  xout[n,k] = sum_j gs[j] * Wlin[j*K+k] + blin[k]
  {
    int k = t & (K - 1), r = t >> LOG2K;
    float part = 0.f;
#pragma unroll
    for (int i = 0; i < K; ++i) {
      int jj = r * K + i;
      part = fmaf(gs[jj], Wlin[jj * K + k], part);
    }
    red[t] = part;                 // safe: all red4 reads done (barrier above)
    __syncthreads();
    if (t < K) {
      float s = blin[t];
#pragma unroll
      for (int r2 = 0; r2 < 256 / K; ++r2) s += red[r2 * K + t];
      xout[(size_t)n * K + t] = s;
    }
  }
}

// ---------------- classifier: sigmoid(sum(fu*fm)) ----------------------------
__global__ void clf_kernel(const int* __restrict__ eli, const float* __restrict__ ela,
                           const float* __restrict__ x2, const float* __restrict__ clfW,
                           const float* __restrict__ clfb, float* __restrict__ out, int L_) {
  int i = blockIdx.x * blockDim.x + threadIdx.x;
  if (i >= L_) return;
  int u = eli[i], m = eli[L_ + i];
  const float4* xup = (const float4*)(x2 + (size_t)u * NH);
  const float4* xmp = (const float4*)(x2 + (size_t)m * NH);
  const float4* eap = (const float4*)(ela + (size_t)i * NH);
  float4 xu0 = xup[0], xu1 = xup[1];
  float4 xm0 = xmp[0], xm1 = xmp[1];
  float4 el0 = eap[0], el1 = eap[1];
  float xu[NH] = {xu0.x, xu0.y, xu0.z, xu0.w, xu1.x, xu1.y, xu1.z, xu1.w};
  float xm[NH] = {xm0.x, xm0.y, xm0.z, xm0.w, xm1.x, xm1.y, xm1.z, xm1.w};
  float el[NH] = {el0.x, el0.y, el0.z, el0.w, el1.x, el1.y, el1.z, el1.w};
  float fu[NH];
#pragma unroll
  for (int k = 0; k < NH; ++k) fu[k] = clfb[k];
#pragma unroll
  for (int j = 0; j < NH; ++j) {
#pragma unroll
    for (int k = 0; k < NH; ++k) fu[k] = fmaf(xu[j], clfW[j * NH + k], fu[k]);
  }
#pragma unroll
  for (int j = 0; j < NH; ++j) {
#pragma unroll
    for (int k = 0; k < NH; ++k) fu[k] = fmaf(el[j], clfW[(NH + j) * NH + k], fu[k]);
  }
  float dot = 0.f;
#pragma unroll
  for (int k = 0; k < NH; ++k) dot += fu[k] * xm[k];
  out[i] = 1.f / (1.f + expf(-dot));
}

extern "C" void kernel_launch(void* const* d_in, const int* in_sizes, int n_in,
                              void* d_out, int out_size, void* d_ws, size_t ws_size,
                              hipStream_t stream) {
  const int* node_ids   = (const int*)d_in[0];
  const int* edge_index = (const int*)d_in[1];
  const int* eli        = (const int*)d_in[2];
  // d_in[3] = topic (unused)
  const float* edge_attr = (const float*)d_in[4];
  const float* ela       = (const float*)d_in[5];
  const float* emb       = (const float*)d_in[6];
  const float* W1     = (const float*)d_in[7];
  const float* a_src1 = (const float*)d_in[8];
  const float* a_dst1 = (const float*)d_in[9];
  const float* We1    = (const float*)d_in[10];
  const float* a_e1   = (const float*)d_in[11];
  const float* b1     = (const float*)d_in[12];
  const float* lin1W  = (const float*)d_in[13];
  const float* lin1b  = (const float*)d_in[14];
  const float* W2     = (const float*)d_in[15];
  const float* a_src2 = (const float*)d_in[16];
  const float* a_dst2 = (const float*)d_in[17];
  const float* We2    = (const float*)d_in[18];
  const float* a_e2   = (const float*)d_in[19];
  const float* b2     = (const float*)d_in[20];
  const float* lin5W  = (const float*)d_in[21];
  const float* lin5b  = (const float*)d_in[22];
  const float* clfW   = (const float*)d_in[23];
  const float* clfb   = (const float*)d_in[24];

  const int N_ = in_sizes[0];
  const int E_ = in_sizes[1] / 2;
  const int L_ = in_sizes[2] / 2;
  const int* src  = edge_index;
  const int* dstp = edge_index + E_;

  char* p = (char*)d_ws;
  auto carve = [&](size_t bytes) -> char* {
    char* r = p;
    p += (bytes + 255) & ~(size_t)255;
    return r;
  };
  bf16*  hbuf   = (bf16*)carve((size_t)N_ * HC * 2);    // 25.6 MB (bf16)
  float* exbuf  = (float*)carve((size_t)E_ * NH * 4);   // 25.6 MB (CSR-sorted)
  float* alsrc  = (float*)carve((size_t)N_ * NH * 4);
  float* aldst  = (float*)carve((size_t)N_ * NH * 4);
  float* x1b    = (float*)carve((size_t)N_ * FIN * 4);
  float* x2b    = (float*)carve((size_t)N_ * NH * 4);
  float* Mbuf   = (float*)carve(128 * 4);
  int*   cnt    = (int*)carve((size_t)N_ * 4);
  int*   rowptr = (int*)carve((size_t)(N_ + 1) * 4);
  int*   fill   = (int*)carve((size_t)N_ * 4);
  int*   perm   = (int*)carve((size_t)E_ * 4);
  int*   srcs   = (int*)carve((size_t)E_ * 4);
  int*   dsts   = (int*)carve((size_t)E_ * 4);

  hipMemsetAsync(cnt, 0, (size_t)N_ * 4, stream);
  int eb = (E_ + 255) / 256;
  count_kernel<<<eb, 256, 0, stream>>>(dstp, cnt, E_);
  scan_kernel<<<1, 1024, 0, stream>>>(cnt, rowptr, fill, N_, E_);
  scatter_kernel<<<eb, 256, 0, stream>>>(src, dstp, fill, perm, srcs, dsts, E_);
  fold_kernel<<<1, 128, 0, stream>>>(We1, a_e1, We2, a_e2, Mbuf);

  int nb4 = (N_ + 3) / 4;
  // ---- layer 1 ----
  node_kernel<<<nb4, 256, 0, stream>>>(emb, node_ids, nullptr, W1, a_src1, a_dst1,
                                       hbuf, alsrc, aldst, N_);
  edge_kernel<<<eb, 256, 0, stream>>>(perm, srcs, dsts, edge_attr, Mbuf, alsrc, aldst,
                                      exbuf, E_);
  agg_lin_kernel<32, 5><<<N_, 256, 0, stream>>>(rowptr, srcs, exbuf, (const uint2*)hbuf,
                                                b1, lin1W, lin1b, x1b);

  // ---- layer 2 ----
  node_kernel<<<nb4, 256, 0, stream>>>(nullptr, nullptr, x1b, W2, a_src2, a_dst2,
                                       hbuf, alsrc, aldst, N_);
  edge_kernel<<<eb, 256, 0, stream>>>(perm, srcs, dsts, edge_attr, Mbuf + 64, alsrc, aldst,
                                      exbuf, E_);
  agg_lin_kernel<8, 3><<<N_, 256, 0, stream>>>(rowptr, srcs, exbuf, (const uint2*)hbuf,
                                               b2, lin5W, lin5b, x2b);

  // ---- classifier ----
  clf_kernel<<<(L_ + 255) / 256, 256, 0, stream>>>(eli, ela, x2b, clfW, clfb,
                                                   (float*)d_out, L_);
}